// Round 4
// baseline (1915.572 us; speedup 1.0000x reference)
//
#include <hip/hip_runtime.h>
#include <hip/hip_bf16.h>

#define BCONST 128
#define LLEN   1024
#define INDIM  64
#define HDIM   256
#define DI     512           // D_INNER
#define NST    16
#define NCLS   12
#define MROWS  (BCONST*LLEN) // 131072

__device__ __forceinline__ float sigmoidf_(float x) {
    return __fdividef(1.0f, 1.0f + __expf(-x));
}

// ---------------------------------------------------------------------------
// fold_k: Wcomb = W_proj_in(64x256) @ W_in(256x1024); bcomb = b_proj_in @ W_in
// Exact: xz = x @ Wcomb + bcomb. grid=256 blocks, thread = one (k,n) pair.
// ---------------------------------------------------------------------------
__global__ __launch_bounds__(256) void fold_k(
    const float* __restrict__ Wp, const float* __restrict__ bp,
    const float* __restrict__ Win, float* __restrict__ Wcomb,
    float* __restrict__ bcomb)
{
    const int k = blockIdx.x >> 2;                    // 0..63
    const int n = (blockIdx.x & 3) * 256 + threadIdx.x; // 0..1023
    float acc = 0.f;
    for (int j = 0; j < 256; j++)
        acc = fmaf(Wp[k * 256 + j], Win[(size_t)j * 1024 + n], acc);
    Wcomb[(size_t)k * 1024 + n] = acc;
    if (k == 0) {
        float bacc = 0.f;
        for (int j = 0; j < 256; j++)
            bacc = fmaf(bp[j], Win[(size_t)j * 1024 + n], bacc);
        bcomb[n] = bacc;
    }
}

// ---------------------------------------------------------------------------
// convgemm_k: xdbl = silu(causal_dwconv(x @ Wcomb[:, :512])) @ W_x  (N=48)
// xm recomputed on the fly per 16-channel K-step: x rows staged once in LDS,
// Wcomb column per thread in registers. BM=128 token rows per block.
// ---------------------------------------------------------------------------
__global__ __launch_bounds__(256) void convgemm_k(
    const float* __restrict__ x, const float* __restrict__ Wcomb,
    const float* __restrict__ bcomb, const float* __restrict__ Wx,
    const float* __restrict__ cw, const float* __restrict__ cb,
    float* __restrict__ xdbl)
{
    __shared__ float xrows[131][68];   // x rows [gm0-3, gm0+128), pad->16B-aligned rows
    __shared__ float rawL[131][17];    // raw xm for current 16 channels
    __shared__ float As[16][132];      // silu(conv(xm)) tile, [k][row]
    __shared__ float Bs[16][48];       // W_x slab
    __shared__ float wtile[64][16];    // Wcomb slab for current K-step
    __shared__ float cwt[16][4];
    __shared__ float cbt[16];
    __shared__ float bct[16];

    const int tid  = threadIdx.x;
    const int tni  = tid & 15;
    const int tmi  = tid >> 4;
    const int mykd = tid & 15;          // (tid + i*256) & 15 is constant
    const int gm0  = blockIdx.x * 128;
    const bool bstart = ((gm0 & (LLEN - 1)) == 0);

    // stage x rows for tokens [gm0-3, gm0+128)
    for (int q = tid; q < 131 * 16; q += 256) {
        int i = q >> 4, jq = (q & 15) * 4;
        int tok = gm0 - 3 + i;
        float4 v = make_float4(0.f, 0.f, 0.f, 0.f);
        if (tok >= 0)
            v = *reinterpret_cast<const float4*>(&x[(size_t)tok * INDIM + jq]);
        *reinterpret_cast<float4*>(&xrows[i][jq]) = v;
    }

    float acc[8][3];
#pragma unroll
    for (int i = 0; i < 8; i++)
#pragma unroll
        for (int j = 0; j < 3; j++) acc[i][j] = 0.f;

    float wcol[64];

    for (int kt = 0; kt < DI; kt += 16) {
        __syncthreads();   // previous GEMM / first-stage done
        // stage Wcomb slab (16 channels), Wx slab, conv params
        for (int q = tid; q < 64 * 16; q += 256) {
            int j = q >> 4, kd = q & 15;
            wtile[j][kd] = Wcomb[(size_t)j * 1024 + kt + kd];
        }
        for (int q = tid; q < 768; q += 256) {
            int kr = q / 48, nc = q - kr * 48;
            Bs[kr][nc] = Wx[(size_t)(kt + kr) * 48 + nc];
        }
        if (tid < 16) { cbt[tid] = cb[kt + tid]; bct[tid] = bcomb[kt + tid]; }
        if (tid < 64) cwt[tid >> 2][tid & 3] = cw[(kt + (tid >> 2)) * 4 + (tid & 3)];
        __syncthreads();

        // my channel's Wcomb column into registers
#pragma unroll
        for (int j = 0; j < 64; j++) wcol[j] = wtile[j][mykd];

        // raw xm for 131 rows x my channel
        for (int q = tid; q < 131 * 16; q += 256) {
            int ro = q >> 4;
            float r = 0.f;
            if (!(bstart && ro < 3)) {
                r = bct[mykd];
#pragma unroll
                for (int j4 = 0; j4 < 16; j4++) {
                    float4 xv = *reinterpret_cast<const float4*>(&xrows[ro][j4 * 4]);
                    r = fmaf(xv.x, wcol[j4 * 4 + 0], r);
                    r = fmaf(xv.y, wcol[j4 * 4 + 1], r);
                    r = fmaf(xv.z, wcol[j4 * 4 + 2], r);
                    r = fmaf(xv.w, wcol[j4 * 4 + 3], r);
                }
            }
            rawL[ro][mykd] = r;
        }
        __syncthreads();

        // conv + silu -> As   (As[kd][row] = silu(sum_t cw[t]*raw[row+t] + cb))
        for (int q = tid; q < 128 * 16; q += 256) {
            int row = q >> 4;
            float v = cbt[mykd];
            v = fmaf(rawL[row + 0][mykd], cwt[mykd][0], v);
            v = fmaf(rawL[row + 1][mykd], cwt[mykd][1], v);
            v = fmaf(rawL[row + 2][mykd], cwt[mykd][2], v);
            v = fmaf(rawL[row + 3][mykd], cwt[mykd][3], v);
            As[mykd][row] = v * sigmoidf_(v);
        }
        __syncthreads();

        // GEMM: 8x3 micro-tile over 16 k
#pragma unroll
        for (int kk = 0; kk < 16; kk++) {
            float4 a0 = *reinterpret_cast<const float4*>(&As[kk][tmi * 8]);
            float4 a1 = *reinterpret_cast<const float4*>(&As[kk][tmi * 8 + 4]);
            float a[8] = {a0.x, a0.y, a0.z, a0.w, a1.x, a1.y, a1.z, a1.w};
            float bb[3] = {Bs[kk][tni * 3], Bs[kk][tni * 3 + 1], Bs[kk][tni * 3 + 2]};
#pragma unroll
            for (int i = 0; i < 8; i++)
#pragma unroll
                for (int j = 0; j < 3; j++)
                    acc[i][j] = fmaf(a[i], bb[j], acc[i][j]);
        }
    }

#pragma unroll
    for (int i = 0; i < 8; i++) {
        const int gm = gm0 + tmi * 8 + i;
#pragma unroll
        for (int j = 0; j < 3; j++)
            xdbl[(size_t)gm * 48 + tni * 3 + j] = acc[i][j];
    }
}

// ---------------------------------------------------------------------------
// scan_k: fused selective scan. One thread per (b,d). xm/z recomputed per
// step from x row (wave-uniform global loads -> scalar path) with Wcomb
// columns held in VGPRs. Rolling conv window, dt GEMV + softplus, state
// update, gating, in-register mean pool.
// ---------------------------------------------------------------------------
__global__ __launch_bounds__(256, 1) void scan_k(
    const float* __restrict__ x, const float* __restrict__ Wcomb,
    const float* __restrict__ bcomb, const float* __restrict__ xdbl,
    const float* __restrict__ Wdt, const float* __restrict__ bdt_g,
    const float* __restrict__ Alog, const float* __restrict__ Dp_g,
    const float* __restrict__ cw, const float* __restrict__ cb,
    float* __restrict__ pooled)
{
    const int tid = threadIdx.x;
    const int b   = blockIdx.y;
    const int d   = blockIdx.x * 256 + tid;

    float wxm[64], wz[64], wdt[16], Av[16], h[16];
#pragma unroll
    for (int j = 0; j < 64; j++) wxm[j] = Wcomb[(size_t)j * 1024 + d];
#pragma unroll
    for (int j = 0; j < 64; j++) wz[j] = Wcomb[(size_t)j * 1024 + 512 + d];
#pragma unroll
    for (int r = 0; r < 16; r++) wdt[r] = Wdt[r * DI + d];
#pragma unroll
    for (int n = 0; n < 16; n++) Av[n] = -__expf(Alog[d * 16 + n]);
#pragma unroll
    for (int n = 0; n < 16; n++) h[n] = 0.f;

    const float bxm = bcomb[d], bz = bcomb[512 + d];
    const float bdt = bdt_g[d], Dpv = Dp_g[d], cbv = cb[d];
    const float4 cwv = *reinterpret_cast<const float4*>(&cw[d * 4]);

    const float* xb  = x + (size_t)b * LLEN * INDIM;
    const float* xdb = xdbl + (size_t)b * LLEN * 48;

    float w0 = 0.f, w1 = 0.f, w2 = 0.f, acc = 0.f;

    for (int l = 0; l < LLEN; l++) {
        const float* xr = xb + (size_t)l * INDIM;   // wave-uniform address
        const float* rw = xdb + (size_t)l * 48;     // wave-uniform address

        float xm_pre = bxm, z_pre = bz;
#pragma unroll
        for (int j4 = 0; j4 < 16; j4++) {
            float4 xv = *reinterpret_cast<const float4*>(xr + j4 * 4);
            xm_pre = fmaf(xv.x, wxm[j4 * 4 + 0], xm_pre);
            xm_pre = fmaf(xv.y, wxm[j4 * 4 + 1], xm_pre);
            xm_pre = fmaf(xv.z, wxm[j4 * 4 + 2], xm_pre);
            xm_pre = fmaf(xv.w, wxm[j4 * 4 + 3], xm_pre);
            z_pre  = fmaf(xv.x, wz[j4 * 4 + 0], z_pre);
            z_pre  = fmaf(xv.y, wz[j4 * 4 + 1], z_pre);
            z_pre  = fmaf(xv.z, wz[j4 * 4 + 2], z_pre);
            z_pre  = fmaf(xv.w, wz[j4 * 4 + 3], z_pre);
        }
        float zs = z_pre * sigmoidf_(z_pre);
        float conv = fmaf(w0, cwv.x, fmaf(w1, cwv.y,
                     fmaf(w2, cwv.z, fmaf(xm_pre, cwv.w, cbv))));
        w0 = w1; w1 = w2; w2 = xm_pre;
        float xv_ = conv * sigmoidf_(conv);

        float dtp = bdt;
#pragma unroll
        for (int r4 = 0; r4 < 4; r4++) {
            float4 rv = *reinterpret_cast<const float4*>(rw + r4 * 4);
            dtp = fmaf(rv.x, wdt[r4 * 4 + 0], dtp);
            dtp = fmaf(rv.y, wdt[r4 * 4 + 1], dtp);
            dtp = fmaf(rv.z, wdt[r4 * 4 + 2], dtp);
            dtp = fmaf(rv.w, wdt[r4 * 4 + 3], dtp);
        }
        float dt = (dtp > 15.f) ? dtp : __logf(1.f + __expf(dtp));
        float dtx = dt * xv_;
        float y = 0.f;
#pragma unroll
        for (int n4 = 0; n4 < 4; n4++) {
            float4 Bv = *reinterpret_cast<const float4*>(rw + 16 + n4 * 4);
            float4 Cv = *reinterpret_cast<const float4*>(rw + 32 + n4 * 4);
            { int n = n4 * 4 + 0; float e = __expf(dt * Av[n]);
              h[n] = fmaf(e, h[n], dtx * Bv.x); y = fmaf(h[n], Cv.x, y); }
            { int n = n4 * 4 + 1; float e = __expf(dt * Av[n]);
              h[n] = fmaf(e, h[n], dtx * Bv.y); y = fmaf(h[n], Cv.y, y); }
            { int n = n4 * 4 + 2; float e = __expf(dt * Av[n]);
              h[n] = fmaf(e, h[n], dtx * Bv.z); y = fmaf(h[n], Cv.z, y); }
            { int n = n4 * 4 + 3; float e = __expf(dt * Av[n]);
              h[n] = fmaf(e, h[n], dtx * Bv.w); y = fmaf(h[n], Cv.w, y); }
        }
        acc = fmaf(y + xv_ * Dpv, zs, acc);
    }
    pooled[(size_t)b * DI + d] = acc * (1.0f / LLEN);
}

// ---------------------------------------------------------------------------
// Classifier: out = ((pooled @ W_out) @ W_c1 + b_c1) @ W_c2 + b_c2
// (mean-pool hoisted before W_out — exact since pooling is linear)
// ---------------------------------------------------------------------------
__global__ __launch_bounds__(256) void cls_k(
    const float* __restrict__ pooled, const float* __restrict__ Wout,
    const float* __restrict__ Wc1, const float* __restrict__ bc1,
    const float* __restrict__ Wc2, const float* __restrict__ bc2,
    float* __restrict__ out)
{
    __shared__ float sp[512];
    __shared__ float s1[256];
    __shared__ float s2[128];
    const int b = blockIdx.x, tid = threadIdx.x;
    sp[tid]       = pooled[(size_t)b * 512 + tid];
    sp[tid + 256] = pooled[(size_t)b * 512 + 256 + tid];
    __syncthreads();
    float a1 = 0.f;
    for (int k = 0; k < 512; k++) a1 = fmaf(sp[k], Wout[(size_t)k * 256 + tid], a1);
    s1[tid] = a1;
    __syncthreads();
    if (tid < 128) {
        float a2 = bc1[tid];
        for (int k = 0; k < 256; k++) a2 = fmaf(s1[k], Wc1[(size_t)k * 128 + tid], a2);
        s2[tid] = a2;
    }
    __syncthreads();
    if (tid < 12) {
        float a3 = bc2[tid];
        for (int k = 0; k < 128; k++) a3 = fmaf(s2[k], Wc2[(size_t)k * 12 + tid], a3);
        out[(size_t)b * 12 + tid] = a3;
    }
}

// ---------------------------------------------------------------------------
extern "C" void kernel_launch(void* const* d_in, const int* in_sizes, int n_in,
                              void* d_out, int out_size, void* d_ws,
                              size_t ws_size, hipStream_t stream)
{
    const float* x      = (const float*)d_in[0];
    const float* Wproj  = (const float*)d_in[1];
    const float* bproj  = (const float*)d_in[2];
    const float* Win    = (const float*)d_in[3];
    const float* convw  = (const float*)d_in[4];
    const float* convb  = (const float*)d_in[5];
    const float* Wx     = (const float*)d_in[6];
    const float* Wdt    = (const float*)d_in[7];
    const float* bdt    = (const float*)d_in[8];
    const float* Alog   = (const float*)d_in[9];
    const float* Dparam = (const float*)d_in[10];
    const float* Wout   = (const float*)d_in[11];
    const float* Wc1    = (const float*)d_in[12];
    const float* bc1    = (const float*)d_in[13];
    const float* Wc2    = (const float*)d_in[14];
    const float* bc2    = (const float*)d_in[15];
    float* out = (float*)d_out;

    // workspace: 65536 + 1024 + 6291456 + 65536 floats = 25.7 MB total
    float* ws     = (float*)d_ws;
    float* Wcomb  = ws;                              // 64*1024
    float* bcomb  = Wcomb + 64 * 1024;               // 1024
    float* xdbl   = bcomb + 1024;                    // M*48
    float* pooled = xdbl + (size_t)MROWS * 48;       // 128*512

    // 1) weight fold: Wcomb = Wproj @ Win, bcomb = bproj @ Win
    fold_k<<<256, 256, 0, stream>>>(Wproj, bproj, Win, Wcomb, bcomb);
    // 2) xdbl = silu(conv(x @ Wcomb_xm)) @ W_x
    convgemm_k<<<MROWS / 128, 256, 0, stream>>>(x, Wcomb, bcomb, Wx, convw,
                                                convb, xdbl);
    // 3) fused scan (recomputes xm,z from x) + gating + mean-pool
    scan_k<<<dim3(2, BCONST), 256, 0, stream>>>(x, Wcomb, bcomb, xdbl, Wdt,
                                                bdt, Alog, Dparam, convw,
                                                convb, pooled);
    // 4) classifier head
    cls_k<<<BCONST, 256, 0, stream>>>(pooled, Wout, Wc1, bc1, Wc2, bc2, out);
}

// Round 5
// 1884.012 us; speedup vs baseline: 1.0168x; 1.0168x over previous
//
#include <hip/hip_runtime.h>
#include <hip/hip_bf16.h>

#define BCONST 128
#define LLEN   1024
#define INDIM  64
#define HDIM   256
#define DI     512           // D_INNER
#define NST    16
#define NCLS   12
#define MROWS  (BCONST*LLEN) // 131072

__device__ __forceinline__ float sigmoidf_(float x) {
    return __fdividef(1.0f, 1.0f + __expf(-x));
}

// ---------------------------------------------------------------------------
// fold_k: Wcomb = W_proj_in(64x256) @ W_in(256x1024); bcomb = b_proj_in @ W_in
// ---------------------------------------------------------------------------
__global__ __launch_bounds__(256) void fold_k(
    const float* __restrict__ Wp, const float* __restrict__ bp,
    const float* __restrict__ Win, float* __restrict__ Wcomb,
    float* __restrict__ bcomb)
{
    const int k = blockIdx.x >> 2;
    const int n = (blockIdx.x & 3) * 256 + threadIdx.x;
    float acc = 0.f;
    for (int j = 0; j < 256; j++)
        acc = fmaf(Wp[k * 256 + j], Win[(size_t)j * 1024 + n], acc);
    Wcomb[(size_t)k * 1024 + n] = acc;
    if (k == 0) {
        float bacc = 0.f;
        for (int j = 0; j < 256; j++)
            bacc = fmaf(bp[j], Win[(size_t)j * 1024 + n], bacc);
        bcomb[n] = bacc;
    }
}

// ---------------------------------------------------------------------------
// convgemm_k: xdbl = silu(causal_dwconv(x @ Wcomb[:, :512])) @ W_x  (N=48)
// ---------------------------------------------------------------------------
__global__ __launch_bounds__(256) void convgemm_k(
    const float* __restrict__ x, const float* __restrict__ Wcomb,
    const float* __restrict__ bcomb, const float* __restrict__ Wx,
    const float* __restrict__ cw, const float* __restrict__ cb,
    float* __restrict__ xdbl)
{
    __shared__ float xrows[131][68];
    __shared__ float rawL[131][17];
    __shared__ float As[16][132];
    __shared__ float Bs[16][48];
    __shared__ float wtile[64][16];
    __shared__ float cwt[16][4];
    __shared__ float cbt[16];
    __shared__ float bct[16];

    const int tid  = threadIdx.x;
    const int tni  = tid & 15;
    const int tmi  = tid >> 4;
    const int mykd = tid & 15;
    const int gm0  = blockIdx.x * 128;
    const bool bstart = ((gm0 & (LLEN - 1)) == 0);

    for (int q = tid; q < 131 * 16; q += 256) {
        int i = q >> 4, jq = (q & 15) * 4;
        int tok = gm0 - 3 + i;
        float4 v = make_float4(0.f, 0.f, 0.f, 0.f);
        if (tok >= 0)
            v = *reinterpret_cast<const float4*>(&x[(size_t)tok * INDIM + jq]);
        *reinterpret_cast<float4*>(&xrows[i][jq]) = v;
    }

    float acc[8][3];
#pragma unroll
    for (int i = 0; i < 8; i++)
#pragma unroll
        for (int j = 0; j < 3; j++) acc[i][j] = 0.f;

    float wcol[64];

    for (int kt = 0; kt < DI; kt += 16) {
        __syncthreads();
        for (int q = tid; q < 64 * 16; q += 256) {
            int j = q >> 4, kd = q & 15;
            wtile[j][kd] = Wcomb[(size_t)j * 1024 + kt + kd];
        }
        for (int q = tid; q < 768; q += 256) {
            int kr = q / 48, nc = q - kr * 48;
            Bs[kr][nc] = Wx[(size_t)(kt + kr) * 48 + nc];
        }
        if (tid < 16) { cbt[tid] = cb[kt + tid]; bct[tid] = bcomb[kt + tid]; }
        if (tid < 64) cwt[tid >> 2][tid & 3] = cw[(kt + (tid >> 2)) * 4 + (tid & 3)];
        __syncthreads();

#pragma unroll
        for (int j = 0; j < 64; j++) wcol[j] = wtile[j][mykd];

        for (int q = tid; q < 131 * 16; q += 256) {
            int ro = q >> 4;
            float r = 0.f;
            if (!(bstart && ro < 3)) {
                r = bct[mykd];
#pragma unroll
                for (int j4 = 0; j4 < 16; j4++) {
                    float4 xv = *reinterpret_cast<const float4*>(&xrows[ro][j4 * 4]);
                    r = fmaf(xv.x, wcol[j4 * 4 + 0], r);
                    r = fmaf(xv.y, wcol[j4 * 4 + 1], r);
                    r = fmaf(xv.z, wcol[j4 * 4 + 2], r);
                    r = fmaf(xv.w, wcol[j4 * 4 + 3], r);
                }
            }
            rawL[ro][mykd] = r;
        }
        __syncthreads();

        for (int q = tid; q < 128 * 16; q += 256) {
            int row = q >> 4;
            float v = cbt[mykd];
            v = fmaf(rawL[row + 0][mykd], cwt[mykd][0], v);
            v = fmaf(rawL[row + 1][mykd], cwt[mykd][1], v);
            v = fmaf(rawL[row + 2][mykd], cwt[mykd][2], v);
            v = fmaf(rawL[row + 3][mykd], cwt[mykd][3], v);
            As[mykd][row] = v * sigmoidf_(v);
        }
        __syncthreads();

#pragma unroll
        for (int kk = 0; kk < 16; kk++) {
            float4 a0 = *reinterpret_cast<const float4*>(&As[kk][tmi * 8]);
            float4 a1 = *reinterpret_cast<const float4*>(&As[kk][tmi * 8 + 4]);
            float a[8] = {a0.x, a0.y, a0.z, a0.w, a1.x, a1.y, a1.z, a1.w};
            float bb[3] = {Bs[kk][tni * 3], Bs[kk][tni * 3 + 1], Bs[kk][tni * 3 + 2]};
#pragma unroll
            for (int i = 0; i < 8; i++)
#pragma unroll
                for (int j = 0; j < 3; j++)
                    acc[i][j] = fmaf(a[i], bb[j], acc[i][j]);
        }
    }

#pragma unroll
    for (int i = 0; i < 8; i++) {
        const int gm = gm0 + tmi * 8 + i;
#pragma unroll
        for (int j = 0; j < 3; j++)
            xdbl[(size_t)gm * 48 + tni * 3 + j] = acc[i][j];
    }
}

// ---------------------------------------------------------------------------
// scanA_k: chunked selective scan, phase A. One thread per (b, d, chunk).
// Computes with unknown h0: local state Hloc, decay product Pprod, gating
// coefficient Kcoef[n] = sum_t p_t[n] C_t[n] zs_t, and local pooled AccLoc.
// ---------------------------------------------------------------------------
__global__ __launch_bounds__(256) void scanA_k(
    const float* __restrict__ x, const float* __restrict__ Wcomb,
    const float* __restrict__ bcomb, const float* __restrict__ xdbl,
    const float* __restrict__ Wdt, const float* __restrict__ bdt_g,
    const float* __restrict__ Alog, const float* __restrict__ Dp_g,
    const float* __restrict__ cw, const float* __restrict__ cb, int Lc,
    float* __restrict__ Pprod, float* __restrict__ Hloc,
    float* __restrict__ Kcoef, float* __restrict__ AccLoc)
{
    const int tid = threadIdx.x;
    const int d   = blockIdx.x * 256 + tid;
    const int c   = blockIdx.y;
    const int P   = gridDim.y;
    const int b   = blockIdx.z;
    const int l0  = c * Lc;

    float wxm[64], wz[64], wdt[16], Av[16], h[16], p[16], K[16];
#pragma unroll
    for (int j = 0; j < 64; j++) wxm[j] = Wcomb[(size_t)j * 1024 + d];
#pragma unroll
    for (int j = 0; j < 64; j++) wz[j] = Wcomb[(size_t)j * 1024 + 512 + d];
#pragma unroll
    for (int r = 0; r < 16; r++) wdt[r] = Wdt[r * DI + d];
#pragma unroll
    for (int n = 0; n < 16; n++) Av[n] = -__expf(Alog[d * 16 + n]);
#pragma unroll
    for (int n = 0; n < 16; n++) { h[n] = 0.f; p[n] = 1.f; K[n] = 0.f; }

    const float bxm = bcomb[d], bz = bcomb[512 + d];
    const float bdt = bdt_g[d], Dpv = Dp_g[d], cbv = cb[d];
    const float4 cwv = *reinterpret_cast<const float4*>(&cw[d * 4]);

    const float* xb  = x + (size_t)b * LLEN * INDIM;
    const float* xdb = xdbl + (size_t)b * LLEN * 48;

    // prologue: conv window = raw xm at l0-3 .. l0-1 (0 before sequence start)
    float wbuf[3];
#pragma unroll
    for (int ii = 0; ii < 3; ii++) {
        int l = l0 - 3 + ii;
        float v = 0.f;
        if (l >= 0) {
            v = bxm;
            const float* xr = xb + (size_t)l * INDIM;
#pragma unroll
            for (int j4 = 0; j4 < 16; j4++) {
                float4 xv = *reinterpret_cast<const float4*>(xr + j4 * 4);
                v = fmaf(xv.x, wxm[j4 * 4 + 0], v);
                v = fmaf(xv.y, wxm[j4 * 4 + 1], v);
                v = fmaf(xv.z, wxm[j4 * 4 + 2], v);
                v = fmaf(xv.w, wxm[j4 * 4 + 3], v);
            }
        }
        wbuf[ii] = v;
    }
    float w0 = wbuf[0], w1 = wbuf[1], w2 = wbuf[2], acc = 0.f;

    for (int t = 0; t < Lc; t++) {
        const int l = l0 + t;
        const float* xr = xb + (size_t)l * INDIM;   // wave-uniform
        const float* rw = xdb + (size_t)l * 48;     // wave-uniform

        float xm_pre = bxm, z_pre = bz;
#pragma unroll
        for (int j4 = 0; j4 < 16; j4++) {
            float4 xv = *reinterpret_cast<const float4*>(xr + j4 * 4);
            xm_pre = fmaf(xv.x, wxm[j4 * 4 + 0], xm_pre);
            xm_pre = fmaf(xv.y, wxm[j4 * 4 + 1], xm_pre);
            xm_pre = fmaf(xv.z, wxm[j4 * 4 + 2], xm_pre);
            xm_pre = fmaf(xv.w, wxm[j4 * 4 + 3], xm_pre);
            z_pre  = fmaf(xv.x, wz[j4 * 4 + 0], z_pre);
            z_pre  = fmaf(xv.y, wz[j4 * 4 + 1], z_pre);
            z_pre  = fmaf(xv.z, wz[j4 * 4 + 2], z_pre);
            z_pre  = fmaf(xv.w, wz[j4 * 4 + 3], z_pre);
        }
        float zs = z_pre * sigmoidf_(z_pre);
        float conv = fmaf(w0, cwv.x, fmaf(w1, cwv.y,
                     fmaf(w2, cwv.z, fmaf(xm_pre, cwv.w, cbv))));
        w0 = w1; w1 = w2; w2 = xm_pre;
        float xv_ = conv * sigmoidf_(conv);

        float dtp = bdt;
#pragma unroll
        for (int r4 = 0; r4 < 4; r4++) {
            float4 rv = *reinterpret_cast<const float4*>(rw + r4 * 4);
            dtp = fmaf(rv.x, wdt[r4 * 4 + 0], dtp);
            dtp = fmaf(rv.y, wdt[r4 * 4 + 1], dtp);
            dtp = fmaf(rv.z, wdt[r4 * 4 + 2], dtp);
            dtp = fmaf(rv.w, wdt[r4 * 4 + 3], dtp);
        }
        float dt = (dtp > 15.f) ? dtp : __logf(1.f + __expf(dtp));
        float dtx = dt * xv_;
        float y = 0.f;
#pragma unroll
        for (int n4 = 0; n4 < 4; n4++) {
            float4 Bv = *reinterpret_cast<const float4*>(rw + 16 + n4 * 4);
            float4 Cv = *reinterpret_cast<const float4*>(rw + 32 + n4 * 4);
            float Ba[4] = {Bv.x, Bv.y, Bv.z, Bv.w};
            float Ca[4] = {Cv.x, Cv.y, Cv.z, Cv.w};
#pragma unroll
            for (int q = 0; q < 4; q++) {
                int n = n4 * 4 + q;
                float e = __expf(dt * Av[n]);
                h[n] = fmaf(e, h[n], dtx * Ba[q]);
                p[n] *= e;
                y = fmaf(h[n], Ca[q], y);
                K[n] = fmaf(p[n], Ca[q] * zs, K[n]);
            }
        }
        acc = fmaf(y + xv_ * Dpv, zs, acc);
    }

    const size_t nbase = ((size_t)(b * P + c) * 16) * DI + d;
#pragma unroll
    for (int n = 0; n < 16; n++) {
        Pprod[nbase + (size_t)n * DI] = p[n];
        Hloc [nbase + (size_t)n * DI] = h[n];
        Kcoef[nbase + (size_t)n * DI] = K[n];
    }
    AccLoc[(size_t)(b * P + c) * DI + d] = acc;
}

// ---------------------------------------------------------------------------
// scanB_k: phase B — chain the P chunks per (b,d) and emit pooled.
// acc += AccLoc_c + sum_n Kcoef_c[n]*h0[n];  h0 = Pprod_c*h0 + Hloc_c.
// ---------------------------------------------------------------------------
__global__ __launch_bounds__(256) void scanB_k(
    const float* __restrict__ Pprod, const float* __restrict__ Hloc,
    const float* __restrict__ Kcoef, const float* __restrict__ AccLoc,
    int P, float* __restrict__ pooled)
{
    const int tid = threadIdx.x;
    const int d   = blockIdx.x * 256 + tid;
    const int b   = blockIdx.y;
    float h[16];
#pragma unroll
    for (int n = 0; n < 16; n++) h[n] = 0.f;
    float acc = 0.f;
    for (int c = 0; c < P; c++) {
        const size_t nbase = ((size_t)(b * P + c) * 16) * DI + d;
        acc += AccLoc[(size_t)(b * P + c) * DI + d];
#pragma unroll
        for (int n = 0; n < 16; n++)
            acc = fmaf(Kcoef[nbase + (size_t)n * DI], h[n], acc);
#pragma unroll
        for (int n = 0; n < 16; n++)
            h[n] = fmaf(Pprod[nbase + (size_t)n * DI], h[n],
                        Hloc[nbase + (size_t)n * DI]);
    }
    pooled[(size_t)b * DI + d] = acc * (1.0f / LLEN);
}

// ---------------------------------------------------------------------------
// Legacy unchunked scan (fallback when ws_size is too small for chunk bufs)
// ---------------------------------------------------------------------------
__global__ __launch_bounds__(256, 1) void scan_k(
    const float* __restrict__ x, const float* __restrict__ Wcomb,
    const float* __restrict__ bcomb, const float* __restrict__ xdbl,
    const float* __restrict__ Wdt, const float* __restrict__ bdt_g,
    const float* __restrict__ Alog, const float* __restrict__ Dp_g,
    const float* __restrict__ cw, const float* __restrict__ cb,
    float* __restrict__ pooled)
{
    const int tid = threadIdx.x;
    const int b   = blockIdx.y;
    const int d   = blockIdx.x * 256 + tid;

    float wxm[64], wz[64], wdt[16], Av[16], h[16];
#pragma unroll
    for (int j = 0; j < 64; j++) wxm[j] = Wcomb[(size_t)j * 1024 + d];
#pragma unroll
    for (int j = 0; j < 64; j++) wz[j] = Wcomb[(size_t)j * 1024 + 512 + d];
#pragma unroll
    for (int r = 0; r < 16; r++) wdt[r] = Wdt[r * DI + d];
#pragma unroll
    for (int n = 0; n < 16; n++) Av[n] = -__expf(Alog[d * 16 + n]);
#pragma unroll
    for (int n = 0; n < 16; n++) h[n] = 0.f;

    const float bxm = bcomb[d], bz = bcomb[512 + d];
    const float bdt = bdt_g[d], Dpv = Dp_g[d], cbv = cb[d];
    const float4 cwv = *reinterpret_cast<const float4*>(&cw[d * 4]);

    const float* xb  = x + (size_t)b * LLEN * INDIM;
    const float* xdb = xdbl + (size_t)b * LLEN * 48;

    float w0 = 0.f, w1 = 0.f, w2 = 0.f, acc = 0.f;

    for (int l = 0; l < LLEN; l++) {
        const float* xr = xb + (size_t)l * INDIM;
        const float* rw = xdb + (size_t)l * 48;
        float xm_pre = bxm, z_pre = bz;
#pragma unroll
        for (int j4 = 0; j4 < 16; j4++) {
            float4 xv = *reinterpret_cast<const float4*>(xr + j4 * 4);
            xm_pre = fmaf(xv.x, wxm[j4 * 4 + 0], xm_pre);
            xm_pre = fmaf(xv.y, wxm[j4 * 4 + 1], xm_pre);
            xm_pre = fmaf(xv.z, wxm[j4 * 4 + 2], xm_pre);
            xm_pre = fmaf(xv.w, wxm[j4 * 4 + 3], xm_pre);
            z_pre  = fmaf(xv.x, wz[j4 * 4 + 0], z_pre);
            z_pre  = fmaf(xv.y, wz[j4 * 4 + 1], z_pre);
            z_pre  = fmaf(xv.z, wz[j4 * 4 + 2], z_pre);
            z_pre  = fmaf(xv.w, wz[j4 * 4 + 3], z_pre);
        }
        float zs = z_pre * sigmoidf_(z_pre);
        float conv = fmaf(w0, cwv.x, fmaf(w1, cwv.y,
                     fmaf(w2, cwv.z, fmaf(xm_pre, cwv.w, cbv))));
        w0 = w1; w1 = w2; w2 = xm_pre;
        float xv_ = conv * sigmoidf_(conv);
        float dtp = bdt;
#pragma unroll
        for (int r4 = 0; r4 < 4; r4++) {
            float4 rv = *reinterpret_cast<const float4*>(rw + r4 * 4);
            dtp = fmaf(rv.x, wdt[r4 * 4 + 0], dtp);
            dtp = fmaf(rv.y, wdt[r4 * 4 + 1], dtp);
            dtp = fmaf(rv.z, wdt[r4 * 4 + 2], dtp);
            dtp = fmaf(rv.w, wdt[r4 * 4 + 3], dtp);
        }
        float dt = (dtp > 15.f) ? dtp : __logf(1.f + __expf(dtp));
        float dtx = dt * xv_;
        float y = 0.f;
#pragma unroll
        for (int n4 = 0; n4 < 4; n4++) {
            float4 Bv = *reinterpret_cast<const float4*>(rw + 16 + n4 * 4);
            float4 Cv = *reinterpret_cast<const float4*>(rw + 32 + n4 * 4);
            { int n = n4 * 4 + 0; float e = __expf(dt * Av[n]);
              h[n] = fmaf(e, h[n], dtx * Bv.x); y = fmaf(h[n], Cv.x, y); }
            { int n = n4 * 4 + 1; float e = __expf(dt * Av[n]);
              h[n] = fmaf(e, h[n], dtx * Bv.y); y = fmaf(h[n], Cv.y, y); }
            { int n = n4 * 4 + 2; float e = __expf(dt * Av[n]);
              h[n] = fmaf(e, h[n], dtx * Bv.z); y = fmaf(h[n], Cv.z, y); }
            { int n = n4 * 4 + 3; float e = __expf(dt * Av[n]);
              h[n] = fmaf(e, h[n], dtx * Bv.w); y = fmaf(h[n], Cv.w, y); }
        }
        acc = fmaf(y + xv_ * Dpv, zs, acc);
    }
    pooled[(size_t)b * DI + d] = acc * (1.0f / LLEN);
}

// ---------------------------------------------------------------------------
__global__ __launch_bounds__(256) void cls_k(
    const float* __restrict__ pooled, const float* __restrict__ Wout,
    const float* __restrict__ Wc1, const float* __restrict__ bc1,
    const float* __restrict__ Wc2, const float* __restrict__ bc2,
    float* __restrict__ out)
{
    __shared__ float sp[512];
    __shared__ float s1[256];
    __shared__ float s2[128];
    const int b = blockIdx.x, tid = threadIdx.x;
    sp[tid]       = pooled[(size_t)b * 512 + tid];
    sp[tid + 256] = pooled[(size_t)b * 512 + 256 + tid];
    __syncthreads();
    float a1 = 0.f;
    for (int k = 0; k < 512; k++) a1 = fmaf(sp[k], Wout[(size_t)k * 256 + tid], a1);
    s1[tid] = a1;
    __syncthreads();
    if (tid < 128) {
        float a2 = bc1[tid];
        for (int k = 0; k < 256; k++) a2 = fmaf(s1[k], Wc1[(size_t)k * 128 + tid], a2);
        s2[tid] = a2;
    }
    __syncthreads();
    if (tid < 12) {
        float a3 = bc2[tid];
        for (int k = 0; k < 128; k++) a3 = fmaf(s2[k], Wc2[(size_t)k * 12 + tid], a3);
        out[(size_t)b * 12 + tid] = a3;
    }
}

// ---------------------------------------------------------------------------
extern "C" void kernel_launch(void* const* d_in, const int* in_sizes, int n_in,
                              void* d_out, int out_size, void* d_ws,
                              size_t ws_size, hipStream_t stream)
{
    const float* x      = (const float*)d_in[0];
    const float* Wproj  = (const float*)d_in[1];
    const float* bproj  = (const float*)d_in[2];
    const float* Win    = (const float*)d_in[3];
    const float* convw  = (const float*)d_in[4];
    const float* convb  = (const float*)d_in[5];
    const float* Wx     = (const float*)d_in[6];
    const float* Wdt    = (const float*)d_in[7];
    const float* bdt    = (const float*)d_in[8];
    const float* Alog   = (const float*)d_in[9];
    const float* Dparam = (const float*)d_in[10];
    const float* Wout   = (const float*)d_in[11];
    const float* Wc1    = (const float*)d_in[12];
    const float* bc1    = (const float*)d_in[13];
    const float* Wc2    = (const float*)d_in[14];
    const float* bc2    = (const float*)d_in[15];
    float* out = (float*)d_out;

    // base workspace: Wcomb 64K + bcomb 1K + xdbl 6.29M + pooled 64K floats
    const size_t baseFloats = 64 * 1024 + 1024 + (size_t)MROWS * 48 + 128 * 512;
    // per-chunk-index buffers: (3*16 + 1) floats per (b,d) = 49*65536 floats
    const size_t perChunkFloats = (size_t)49 * BCONST * DI;

    // choose largest P in {8,4,2,1} that fits ws_size (deterministic per run)
    int P = 8;
    while (P > 1 && (baseFloats + (size_t)P * perChunkFloats) * 4 > ws_size)
        P >>= 1;
    const bool chunked =
        (baseFloats + (size_t)P * perChunkFloats) * 4 <= ws_size;

    float* ws     = (float*)d_ws;
    float* Wcomb  = ws;                              // 64*1024
    float* bcomb  = Wcomb + 64 * 1024;               // 1024
    float* xdbl   = bcomb + 1024;                    // M*48
    float* pooled = xdbl + (size_t)MROWS * 48;       // 128*512
    float* Pprod  = pooled + 128 * 512;              // B*P*16*DI
    float* Hloc   = Pprod + (size_t)BCONST * P * 16 * DI;
    float* Kcoef  = Hloc  + (size_t)BCONST * P * 16 * DI;
    float* AccLoc = Kcoef + (size_t)BCONST * P * 16 * DI;  // B*P*DI

    fold_k<<<256, 256, 0, stream>>>(Wproj, bproj, Win, Wcomb, bcomb);
    convgemm_k<<<MROWS / 128, 256, 0, stream>>>(x, Wcomb, bcomb, Wx, convw,
                                                convb, xdbl);
    if (chunked) {
        const int Lc = LLEN / P;
        scanA_k<<<dim3(DI / 256, P, BCONST), 256, 0, stream>>>(
            x, Wcomb, bcomb, xdbl, Wdt, bdt, Alog, Dparam, convw, convb, Lc,
            Pprod, Hloc, Kcoef, AccLoc);
        scanB_k<<<dim3(DI / 256, BCONST), 256, 0, stream>>>(
            Pprod, Hloc, Kcoef, AccLoc, P, pooled);
    } else {
        scan_k<<<dim3(DI / 256, BCONST), 256, 0, stream>>>(
            x, Wcomb, bcomb, xdbl, Wdt, bdt, Alog, Dparam, convw, convb,
            pooled);
    }
    cls_k<<<BCONST, 256, 0, stream>>>(pooled, Wout, Wc1, bc1, Wc2, bc2, out);
}